// Round 2
// baseline (13942.961 us; speedup 1.0000x reference)
//
#include <hip/hip_runtime.h>
#include <stdint.h>

#define TSTEPS   4096
#define NEG_VAL  -1000000000.0f
#define RINGN    32
#define L0WG     8
#define L1WG     16
#define NWG      (L0WG + L1WG)

// ---------------- workspace layout (bytes) ----------------
#define GI0_OFF   0                                   // T*1536 f32 = 25165824
#define H1_OFF    (TSTEPS*1536*4)                     // T*512 f32  = 8388608
#define RING0_OFF (H1_OFF + TSTEPS*512*4)             // 32*512*8   = 131072
#define RING1_OFF (RING0_OFF + RINGN*512*8)           // 32*512*8   = 131072
#define PROG_OFF  (RING1_OFF + RINGN*512*8)           // 24*64B
#define WS_NEED   ((size_t)PROG_OFF + NWG*64)

// ---------------- helpers ----------------
static __device__ __forceinline__ unsigned long long ld_a64(const unsigned long long* p){
  return __hip_atomic_load(p, __ATOMIC_RELAXED, __HIP_MEMORY_SCOPE_AGENT);
}
static __device__ __forceinline__ void st_a64(unsigned long long* p, unsigned long long v){
  __hip_atomic_store(p, v, __ATOMIC_RELAXED, __HIP_MEMORY_SCOPE_AGENT);
}
static __device__ __forceinline__ float sigmoidf_(float x){
  return 1.0f / (1.0f + __expf(-x));
}
static __device__ __forceinline__ float tanhf_(float x){
  float ax = fabsf(x);
  float e  = __expf(-2.0f*ax);
  float t  = (1.0f - e) / (1.0f + e);
  return copysignf(t, x);
}

// tree-reduce 16 per-lane partials (rows) across 64 lanes with row multiplexing:
// 17 shuffles/lane instead of 16 rows x 6 levels = 96.
// On return, lanes 0..15 hold full sums; lane l holds row
// R(l) = 8*(l&1) + 4*((l>>1)&1) + 2*((l>>2)&1) + ((l>>3)&1).
static __device__ __forceinline__ float reduce16(const float acc[16], int lane){
  float s8[8];
  #pragma unroll
  for (int i=0;i<8;++i){
    float keep = (lane&1) ? acc[8+i] : acc[i];
    float send = (lane&1) ? acc[i]   : acc[8+i];
    s8[i] = keep + __shfl_xor(send, 1, 64);
  }
  float s4[4];
  #pragma unroll
  for (int i=0;i<4;++i){
    float keep = (lane&2) ? s8[4+i] : s8[i];
    float send = (lane&2) ? s8[i]   : s8[4+i];
    s4[i] = keep + __shfl_xor(send, 2, 64);
  }
  float s2[2];
  #pragma unroll
  for (int i=0;i<2;++i){
    float keep = (lane&4) ? s4[2+i] : s4[i];
    float send = (lane&4) ? s4[i]   : s4[2+i];
    s2[i] = keep + __shfl_xor(send, 4, 64);
  }
  float keep = (lane&8) ? s2[1] : s2[0];
  float send = (lane&8) ? s2[0] : s2[1];
  float s1 = keep + __shfl_xor(send, 8, 64);
  s1 += __shfl_xor(s1, 16, 64);
  s1 += __shfl_xor(s1, 32, 64);
  return s1;
}
static __device__ __forceinline__ int rowmap(int lane){
  return 8*(lane&1) + 4*((lane>>1)&1) + 2*((lane>>2)&1) + ((lane>>3)&1);
}

// ---------------- persistent 2-layer GRU scan ----------------
// 24 WGs x 768 threads (12 waves). WG 0..7: layer0 (64 h each).
// WG 8..23: layer1 (32 h each). Weights in VGPRs: w[16][8] per thread.
__global__ __launch_bounds__(768,3) void gru_scan(
    const float* __restrict__ gi0,
    const float* __restrict__ hprev,
    const float* __restrict__ Whh0,
    const float* __restrict__ Wih1,
    const float* __restrict__ Whh1,
    const float* __restrict__ bhh0,
    const float* __restrict__ bih1,
    const float* __restrict__ bhh1,
    float* __restrict__ H1hist,
    unsigned long long* ring0,
    unsigned long long* ring1,
    unsigned* prog,
    float* __restrict__ hnext)
{
  const int wg   = blockIdx.x;
  const int tid  = threadIdx.x;
  const int wave = tid >> 6;
  const int lane = tid & 63;

  __shared__ float hbuf0[512];
  __shared__ float hbuf1[512];
  __shared__ float sc[192];

  long budget = (1L<<22);

  if (wg < L0WG) {
    // ================= layer 0 =================
    const int obase = wg*64;
    float w[16][8];
    #pragma unroll
    for (int k=0;k<16;++k){
      const int r = wave*16 + k;
      const int g = r >> 6, o = r & 63;
      const float* wp = Whh0 + ((size_t)(g*512 + obase + o))*512 + lane;
      #pragma unroll
      for (int j=0;j<8;++j) w[k][j] = wp[j*64];
    }
    float hreg=0.f, br=0.f, bz=0.f, bn_=0.f;
    if (tid < 64){
      hreg = hprev[obase+tid];
      br  = bhh0[obase+tid]; bz = bhh0[512+obase+tid]; bn_ = bhh0[1024+obase+tid];
    }
    for (int t=0; t<TSTEPS; ++t){
      float gr=0.f, gz=0.f, gn=0.f;
      if (tid < 64){                        // prefetch gi0 early (hidden under poll)
        const float* gp = gi0 + (size_t)t*1536 + obase + tid;
        gr = gp[0]; gz = gp[512]; gn = gp[1024];
      }
      if (wave < 8){
        const int word = wave*64 + lane;
        if (t == 0){
          hbuf0[word] = hprev[word];
        } else {
          const unsigned long long* p = ring0 + (size_t)((t-1)&(RINGN-1))*512 + word;
          unsigned long long v;
          for(;;){ v = ld_a64(p); if ((unsigned)(v>>32) == (unsigned)t) break;
                   if (--budget < 0) break; }
          hbuf0[word] = __uint_as_float((unsigned)v);
        }
      } else if (wave == 8 && lane == 0){
        if ((t & 3) == 0 && t >= 2)         // publish: consumed ring0 data <= t-2
          __hip_atomic_store(prog + wg*16, (unsigned)(t-2),
                             __ATOMIC_RELEASE, __HIP_MEMORY_SCOPE_AGENT);
        if ((t & 7) == 0 && t >= 32){       // flow check: overwrite safety, lag tol ~20
          const int need = t - 24;
          for (int c=0;c<NWG;++c){
            const unsigned* pp = prog + c*16;
            while ((int)__hip_atomic_load(pp, __ATOMIC_RELAXED, __HIP_MEMORY_SCOPE_AGENT) < need){
              if (--budget < 0) break;
            }
          }
        }
      }
      __syncthreads();
      float hj[8];
      #pragma unroll
      for (int j=0;j<8;++j) hj[j] = hbuf0[j*64 + lane];
      float acc[16];
      #pragma unroll
      for (int k=0;k<16;++k){
        float a = 0.f;
        #pragma unroll
        for (int j=0;j<8;++j) a = fmaf(w[k][j], hj[j], a);
        acc[k] = a;
      }
      const float s1 = reduce16(acc, lane);
      if (lane < 16) sc[wave*16 + rowmap(lane)] = s1;
      __syncthreads();
      if (tid < 64){
        const float ghr = sc[tid]     + br;
        const float ghz = sc[64+tid]  + bz;
        const float ghn = sc[128+tid] + bn_;
        const float r = sigmoidf_(gr + ghr);
        const float z = sigmoidf_(gz + ghz);
        const float n = tanhf_(gn + r*ghn);
        const float h = (1.f - z)*n + z*hreg;
        hreg = h;
        st_a64(ring0 + (size_t)(t&(RINGN-1))*512 + obase + tid,
               ((unsigned long long)(unsigned)(t+1)<<32) |
               (unsigned long long)__float_as_uint(h));
        if (t == TSTEPS-1) hnext[obase+tid] = h;
      }
    }
  } else {
    // ================= layer 1 =================
    const int q = wg - L0WG;
    const int qbase = q*32;
    float w[16][8];
    #pragma unroll
    for (int k=0;k<16;++k){
      const int rw = wave*16 + k;           // 0..95: Wih1 (dot h0); 96..191: Whh1 (dot h1)
      const bool ih = rw < 96;
      const int rr = ih ? rw : rw - 96;
      const int g = rr >> 5, o = rr & 31;
      const float* W = ih ? Wih1 : Whh1;
      const float* wp = W + ((size_t)(g*512 + qbase + o))*512 + lane;
      #pragma unroll
      for (int j=0;j<8;++j) w[k][j] = wp[j*64];
    }
    float hreg=0.f, bir=0.f,biz=0.f,bin_=0.f, bhr=0.f,bhz=0.f,bhn=0.f;
    if (tid < 32){
      hreg = hprev[512+qbase+tid];
      bir = bih1[qbase+tid]; biz = bih1[512+qbase+tid]; bin_ = bih1[1024+qbase+tid];
      bhr = bhh1[qbase+tid]; bhz = bhh1[512+qbase+tid]; bhn  = bhh1[1024+qbase+tid];
    }
    for (int s=0; s<TSTEPS; ++s){
      if (wave < 8){
        // poll h0(s) from ring0, tag s+1
        const int word = wave*64 + lane;
        const unsigned long long* p = ring0 + (size_t)(s&(RINGN-1))*512 + word;
        unsigned long long v;
        for(;;){ v = ld_a64(p); if ((unsigned)(v>>32) == (unsigned)(s+1)) break;
                 if (--budget < 0) break; }
        hbuf0[word] = __uint_as_float((unsigned)v);
      } else {
        // waves 8..11: poll h1(s-1) from ring1 (2 words per lane), tag s
        if (wave == 11 && lane == 0){
          if ((s & 3) == 0 && s >= 1)
            __hip_atomic_store(prog + wg*16, (unsigned)(s-1),
                               __ATOMIC_RELEASE, __HIP_MEMORY_SCOPE_AGENT);
          if ((s & 7) == 0 && s >= 32){
            const int need = s - 24;
            for (int c=0;c<NWG;++c){
              const unsigned* pp = prog + c*16;
              while ((int)__hip_atomic_load(pp, __ATOMIC_RELAXED, __HIP_MEMORY_SCOPE_AGENT) < need){
                if (--budget < 0) break;
              }
            }
          }
        }
        const int w0 = (wave-8)*128 + lane;
        if (s == 0){
          hbuf1[w0]    = hprev[512+w0];
          hbuf1[w0+64] = hprev[512+w0+64];
        } else {
          const unsigned long long* base = ring1 + (size_t)((s-1)&(RINGN-1))*512;
          unsigned long long v;
          for(;;){ v = ld_a64(base+w0); if ((unsigned)(v>>32) == (unsigned)s) break;
                   if (--budget < 0) break; }
          hbuf1[w0] = __uint_as_float((unsigned)v);
          for(;;){ v = ld_a64(base+w0+64); if ((unsigned)(v>>32) == (unsigned)s) break;
                   if (--budget < 0) break; }
          hbuf1[w0+64] = __uint_as_float((unsigned)v);
        }
      }
      __syncthreads();
      const float* hsrc = (wave < 6) ? hbuf0 : hbuf1;
      float hj[8];
      #pragma unroll
      for (int j=0;j<8;++j) hj[j] = hsrc[j*64 + lane];
      float acc[16];
      #pragma unroll
      for (int k=0;k<16;++k){
        float a = 0.f;
        #pragma unroll
        for (int j=0;j<8;++j) a = fmaf(w[k][j], hj[j], a);
        acc[k] = a;
      }
      const float s1 = reduce16(acc, lane);
      if (lane < 16) sc[wave*16 + rowmap(lane)] = s1;
      __syncthreads();
      if (tid < 32){
        const float gir = sc[tid]      + bir;
        const float giz = sc[32+tid]   + biz;
        const float gin = sc[64+tid]   + bin_;
        const float ghr = sc[96+tid]   + bhr;
        const float ghz = sc[128+tid]  + bhz;
        const float ghn = sc[160+tid]  + bhn;
        const float r = sigmoidf_(gir + ghr);
        const float z = sigmoidf_(giz + ghz);
        const float n = tanhf_(gin + r*ghn);
        const float h = (1.f - z)*n + z*hreg;
        hreg = h;
        st_a64(ring1 + (size_t)(s&(RINGN-1))*512 + qbase + tid,
               ((unsigned long long)(unsigned)(s+1)<<32) |
               (unsigned long long)__float_as_uint(h));
        H1hist[(size_t)s*512 + qbase + tid] = h;
        if (s == TSTEPS-1) hnext[512+qbase+tid] = h;
      }
    }
  }
}

// ---------------- tiled fp32 GEMM: C[m][n] = sum_k A[m][k]*B[n][k] + bias[n] ----------------
// BM=BN=64, BK=32, 256 threads, 4x4 per thread. EPI=1: relu then mask(n)==0 -> NEG.
template<int EPI>
__global__ __launch_bounds__(256) void gemm_nt(
    const float* __restrict__ A, int lda,
    const float* __restrict__ B, int ldb,
    float* __restrict__ C, int ldc,
    const float* __restrict__ bias,
    const int* __restrict__ mask,
    int K)
{
  __shared__ __align__(16) float As[32][68];
  __shared__ __align__(16) float Bs[32][68];
  const int bm = blockIdx.y*64, bn = blockIdx.x*64;
  const int tid = threadIdx.x;
  const int tm = tid>>4, tn = tid&15;
  float acc[4][4] = {};
  const int m0 = tid>>2, kk0 = (tid&3)*8;
  for (int k0=0; k0<K; k0+=32){
    #pragma unroll
    for (int j=0;j<8;++j) As[kk0+j][m0] = A[(size_t)(bm+m0)*lda + k0+kk0+j];
    #pragma unroll
    for (int j=0;j<8;++j) Bs[kk0+j][m0] = B[(size_t)(bn+m0)*ldb + k0+kk0+j];
    __syncthreads();
    #pragma unroll
    for (int kk=0;kk<32;++kk){
      const float4 av = *(const float4*)&As[kk][tm*4];
      const float4 bv = *(const float4*)&Bs[kk][tn*4];
      acc[0][0]=fmaf(av.x,bv.x,acc[0][0]); acc[0][1]=fmaf(av.x,bv.y,acc[0][1]);
      acc[0][2]=fmaf(av.x,bv.z,acc[0][2]); acc[0][3]=fmaf(av.x,bv.w,acc[0][3]);
      acc[1][0]=fmaf(av.y,bv.x,acc[1][0]); acc[1][1]=fmaf(av.y,bv.y,acc[1][1]);
      acc[1][2]=fmaf(av.y,bv.z,acc[1][2]); acc[1][3]=fmaf(av.y,bv.w,acc[1][3]);
      acc[2][0]=fmaf(av.z,bv.x,acc[2][0]); acc[2][1]=fmaf(av.z,bv.y,acc[2][1]);
      acc[2][2]=fmaf(av.z,bv.z,acc[2][2]); acc[2][3]=fmaf(av.z,bv.w,acc[2][3]);
      acc[3][0]=fmaf(av.w,bv.x,acc[3][0]); acc[3][1]=fmaf(av.w,bv.y,acc[3][1]);
      acc[3][2]=fmaf(av.w,bv.z,acc[3][2]); acc[3][3]=fmaf(av.w,bv.w,acc[3][3]);
    }
    __syncthreads();
  }
  #pragma unroll
  for (int i=0;i<4;++i){
    #pragma unroll
    for (int j=0;j<4;++j){
      const int mm = bm + tm*4 + i, cc = bn + tn*4 + j;
      float v = acc[i][j] + bias[cc];
      if (EPI){
        v = fmaxf(v, 0.f);
        if (mask[cc] == 0) v = NEG_VAL;
      }
      C[(size_t)mm*ldc + cc] = v;
    }
  }
}

// ---------------- launch ----------------
extern "C" void kernel_launch(void* const* d_in, const int* in_sizes, int n_in,
                              void* d_out, int out_size, void* d_ws, size_t ws_size,
                              hipStream_t stream)
{
  const float* state = (const float*)d_in[0];   // (4096, 129)
  const float* hprev = (const float*)d_in[1];   // (2, 512)
  const int*   mask  = (const int*)d_in[2];     // (64, 64)
  const float* Wih0  = (const float*)d_in[3];   // (1536, 128)
  const float* Whh0  = (const float*)d_in[4];   // (1536, 512)
  const float* bih0  = (const float*)d_in[5];
  const float* bhh0  = (const float*)d_in[6];
  const float* Wih1  = (const float*)d_in[7];   // (1536, 512)
  const float* Whh1  = (const float*)d_in[8];   // (1536, 512)
  const float* bih1  = (const float*)d_in[9];
  const float* bhh1  = (const float*)d_in[10];
  const float* Wfc   = (const float*)d_in[11];  // (4096, 512)
  const float* bfc   = (const float*)d_in[12];

  if (ws_size < WS_NEED) return;   // fail loudly via poisoned output

  float* out = (float*)d_out;
  char*  ws  = (char*)d_ws;
  float* gi0 = (float*)(ws + GI0_OFF);
  float* H1  = (float*)(ws + H1_OFF);
  unsigned long long* ring0 = (unsigned long long*)(ws + RING0_OFF);
  unsigned long long* ring1 = (unsigned long long*)(ws + RING1_OFF);
  unsigned* prog = (unsigned*)(ws + PROG_OFF);

  // reset rings + progress each call (harness does not re-poison between replays)
  (void)hipMemsetAsync(ws + RING0_OFF, 0, (size_t)(WS_NEED - RING0_OFF), stream);

  // gi0 = x @ Wih0^T + bih0   (M=4096, N=1536, K=128)
  {
    dim3 grid(1536/64, 4096/64);
    gemm_nt<0><<<grid, 256, 0, stream>>>(state+1, 129, Wih0, 128, gi0, 1536,
                                         bih0, nullptr, 128);
  }

  // sequential 2-layer GRU scan
  gru_scan<<<NWG, 768, 0, stream>>>(gi0, hprev, Whh0, Wih1, Whh1,
                                    bhh0, bih1, bhh1,
                                    H1, ring0, ring1, prog,
                                    out + (size_t)4096*4096);

  // logits = relu(H1 @ Wfc^T + bfc), masked   (M=4096, N=4096, K=512)
  {
    dim3 grid(4096/64, 4096/64);
    gemm_nt<1><<<grid, 256, 0, stream>>>(H1, 512, Wfc, 512, out, 4096,
                                         bfc, mask, 512);
  }
}